// Round 17
// baseline (152.814 us; speedup 1.0000x reference)
//
#include <hip/hip_runtime.h>
#include <hip/hip_bf16.h>

#define S_ 256
#define D_ 256
#define K_ 64
#define SIN 512
#define F4H 512

typedef unsigned short u16;
typedef __attribute__((ext_vector_type(8))) short short8;
typedef __attribute__((ext_vector_type(4))) float f32x4;

__device__ __forceinline__ float rcpf(float x) { return __builtin_amdgcn_rcpf(x); }
__device__ __forceinline__ float fast_sigmoid(float x) {
  return rcpf(1.0f + __expf(-x));
}
__device__ __forceinline__ float fast_tanh(float x) {
  return 1.0f - 2.0f * rcpf(__expf(2.0f * x) + 1.0f);
}
__device__ __forceinline__ u16 f2bf(float f) {   // RNE f32->bf16
  unsigned int u = __float_as_uint(f);
  return (u16)((u + 0x7fff + ((u >> 16) & 1)) >> 16);
}
__device__ __forceinline__ float bf2f(u16 u) {
  return __uint_as_float(((unsigned int)u) << 16);
}

// prologue: weights f32->bf16 transposed [layer*2+dir][n][k] (z<4);
// x f32->bf16 transposed xT[b][d][l] (z>=4); act decode in z==0 block.
__global__ __launch_bounds__(256) void k_prep(const float* __restrict__ sw_f,
    const float* __restrict__ sw_b, u16* __restrict__ wt,
    const float* __restrict__ x, u16* __restrict__ xT,
    const int* __restrict__ araw, int* __restrict__ act_out,
    int* __restrict__ status) {
  if (blockIdx.x == 0 && blockIdx.y == 0 && blockIdx.z == 0 && threadIdx.x == 0) {
    bool oddzero = true;
    for (int i = 1; i < 16; i += 2) oddzero = oddzero && (araw[i] == 0);
    bool ok = true;
    for (int b = 0; b < 16; ++b) {
      int v = oddzero ? araw[2 * b] : araw[b];
      act_out[b] = (v < 0) ? 0 : (v > 7 ? 7 : v);
      ok = ok && (v >= 0 && v < 8);
    }
    *status = ok ? 1 : 0;
  }
  __shared__ u16 tile[64][66];
  int tj = threadIdx.x & 63, ti = threadIdx.x >> 6;
  int z = blockIdx.z;
  if (z < 4) {                         // SRU weight transpose
    int layer = z >> 1;
    const float* src = (z & 1) ? sw_b : sw_f;
    int k0 = blockIdx.x * 64, n0 = blockIdx.y * 64;
#pragma unroll
    for (int i = ti; i < 64; i += 4)
      tile[i][tj] = f2bf(src[layer * 262144 + (k0 + i) * 512 + n0 + tj]);
    __syncthreads();
#pragma unroll
    for (int j = ti; j < 64; j += 4)
      wt[z * 262144 + (n0 + j) * 512 + k0 + tj] = tile[tj][j];
  } else {                             // x transpose -> xT[b][d][l] bf16
    if (blockIdx.x >= 4 || blockIdx.y >= 4) return;
    int b = z - 4;
    int l0 = blockIdx.x * 64, d0 = blockIdx.y * 64;
#pragma unroll
    for (int i = ti; i < 64; i += 4)
      tile[i][tj] = f2bf(x[b * 65536 + (l0 + i) * 256 + d0 + tj]);
    __syncthreads();
#pragma unroll
    for (int j = ti; j < 64; j += 4)
      xT[b * 65536 + (d0 + j) * 256 + l0 + tj] = tile[tj][j];
  }
}

// 16-row tile GEMM -> TRANSPOSED store: xtT[(b*64+n)*256+l]
__global__ __launch_bounds__(256) void k_xt(const float* __restrict__ x,
    const int* __restrict__ act, const float* __restrict__ w1,
    const float* __restrict__ b1, float* __restrict__ xtT) {
  __shared__ float As[16][17], Bs[16][68];
  int b = blockIdx.y;
  int a = act[b];
  int l0 = blockIdx.x * 16;
  const float* A = x + b * (S_ * D_);
  const float* W = w1 + a * (D_ * K_);
  int tid = threadIdx.x;
  int ty = tid >> 4, tx = tid & 15;
  float acc[4] = {};
  for (int kk = 0; kk < D_; kk += 16) {
    As[ty][tx] = A[(l0 + ty) * D_ + kk + tx];
    *(float4*)&Bs[ty][tx << 2] = *(const float4*)(W + (kk + ty) * K_ + (tx << 2));
    __syncthreads();
#pragma unroll
    for (int k = 0; k < 16; ++k) {
      float av = As[ty][k];
      acc[0] += av * Bs[k][(tx << 2) + 0];
      acc[1] += av * Bs[k][(tx << 2) + 1];
      acc[2] += av * Bs[k][(tx << 2) + 2];
      acc[3] += av * Bs[k][(tx << 2) + 3];
    }
    __syncthreads();
  }
#pragma unroll
  for (int j = 0; j < 4; ++j) {
    int n = (tx << 2) + j;
    xtT[(b << 14) + n * 256 + l0 + ty] = acc[j] + b1[a * K_ + n];
  }
}

// 16-row tile: yt[((s0+r)*16+b)*64+n]
__global__ __launch_bounds__(256) void k_yt(const float* __restrict__ curb,
    int sstride, int bstride, const int* __restrict__ act,
    const float* __restrict__ w2, const float* __restrict__ b2,
    float* __restrict__ yt) {
  __shared__ float As[16][17], Bs[16][68];
  int b = blockIdx.y;
  int a = act[b];
  int s0 = blockIdx.x * 16;
  const float* A = curb + b * bstride;
  const float* W = w2 + a * (D_ * K_);
  int tid = threadIdx.x;
  int ty = tid >> 4, tx = tid & 15;
  float acc[4] = {};
  for (int kk = 0; kk < D_; kk += 16) {
    As[ty][tx] = A[(s0 + ty) * sstride + kk + tx];
    *(float4*)&Bs[ty][tx << 2] = *(const float4*)(W + (kk + ty) * K_ + (tx << 2));
    __syncthreads();
#pragma unroll
    for (int k = 0; k < 16; ++k) {
      float av = As[ty][k];
      acc[0] += av * Bs[k][(tx << 2) + 0];
      acc[1] += av * Bs[k][(tx << 2) + 1];
      acc[2] += av * Bs[k][(tx << 2) + 2];
      acc[3] += av * Bs[k][(tx << 2) + 3];
    }
    __syncthreads();
  }
  float4 o;
  o.x = acc[0] + b2[a * K_ + (tx << 2) + 0];
  o.y = acc[1] + b2[a * K_ + (tx << 2) + 1];
  o.z = acc[2] + b2[a * K_ + (tx << 2) + 2];
  o.w = acc[3] + b2[a * K_ + (tx << 2) + 3];
  *(float4*)(yt + ((s0 + ty) * 16 + b) * K_ + (tx << 2)) = o;
}

// scores+softmax, 8 s-rows/block, 512 blocks; bf16 probs out
__global__ __launch_bounds__(256) void k_score(const float* __restrict__ xtT,
    const float* __restrict__ yt, const float* __restrict__ v,
    const int* __restrict__ act, const unsigned char* __restrict__ xmask,
    u16* __restrict__ scores) {
  __shared__ float yts[8][K_], vas[K_];
  __shared__ float redm[8][4], reds[8][4];
  int tid = threadIdx.x;               // = l
  int bid = blockIdx.x;                // s8*16 + b
  int b = bid & 15, s8 = bid >> 4;     // rows s8*8 .. +7
  int a = act[b];
  if (tid < 64) vas[tid] = v[a * K_ + tid];
#pragma unroll
  for (int i = tid; i < 512; i += 256) {
    int row = i >> 6, k = i & 63;
    yts[row][k] = yt[((s8 * 8 + row) * 16 + b) * K_ + k];
  }
  __syncthreads();
  float acc[8] = {};
  {
    const float* xb = xtT + (b << 14) + tid;
#pragma unroll
    for (int k = 0; k < 64; ++k) {
      float xv = xb[k * 256];
      float vv = vas[k];
#pragma unroll
      for (int r = 0; r < 8; ++r)
        acc[r] += vv * fast_tanh(xv + yts[r][k]);
    }
    if (xmask[b * S_ + tid]) {
#pragma unroll
      for (int r = 0; r < 8; ++r) acc[r] = -1e30f;
    }
  }
  int wid = tid >> 6;
  float m[8];
#pragma unroll
  for (int r = 0; r < 8; ++r) m[r] = acc[r];
#pragma unroll
  for (int d = 32; d; d >>= 1)
#pragma unroll
    for (int r = 0; r < 8; ++r) m[r] = fmaxf(m[r], __shfl_xor(m[r], d));
  if ((tid & 63) == 0) {
#pragma unroll
    for (int r = 0; r < 8; ++r) redm[r][wid] = m[r];
  }
  __syncthreads();
#pragma unroll
  for (int r = 0; r < 8; ++r)
    m[r] = fmaxf(fmaxf(redm[r][0], redm[r][1]), fmaxf(redm[r][2], redm[r][3]));
  float p[8], s[8];
#pragma unroll
  for (int r = 0; r < 8; ++r) { p[r] = __expf(acc[r] - m[r]); s[r] = p[r]; }
#pragma unroll
  for (int d = 32; d; d >>= 1)
#pragma unroll
    for (int r = 0; r < 8; ++r) s[r] += __shfl_xor(s[r], d);
  if ((tid & 63) == 0) {
#pragma unroll
    for (int r = 0; r < 8; ++r) reds[r][wid] = s[r];
  }
  __syncthreads();
#pragma unroll
  for (int r = 0; r < 8; ++r)
    s[r] = reds[r][0] + reds[r][1] + reds[r][2] + reds[r][3];
  u16* dst = scores + ((s8 * 8) * 16 + b) * 256 + tid;
#pragma unroll
  for (int r = 0; r < 8; ++r)
    dst[r * 16 * 256] = f2bf(p[r] * rcpf(s[r]));
}

// bf16 MFMA pool: pools = att(bf16) @ xT(bf16)^T per batch; 64x64 tile, BK=64
__global__ __launch_bounds__(256) void k_poolm(const u16* __restrict__ scores,
    const u16* __restrict__ xT, const float* __restrict__ curb,
    int sstride, int bstride, u16* __restrict__ inp) {
  __shared__ u16 As[64][72];
  __shared__ u16 Bs[64][72];
  int b = blockIdx.z;
  int m0 = blockIdx.x * 64, n0 = blockIdx.y * 64;   // s, d
  int tid = threadIdx.x;
  int wid = tid >> 6, lane = tid & 63;
  int wm = wid >> 1, wn = wid & 1;
  f32x4 acc[2][2];
#pragma unroll
  for (int i = 0; i < 2; ++i)
#pragma unroll
    for (int j = 0; j < 2; ++j) acc[i][j] = (f32x4){0.f, 0.f, 0.f, 0.f};
  int srow = tid >> 2, soff = (tid & 3) * 16;
  int lrow = lane & 15, lk = (lane >> 4) << 3;
  for (int kk = 0; kk < 256; kk += 64) {
    const u16* ga = scores + ((m0 + srow) * 16 + b) * 256 + kk + soff;
    const u16* gb = xT + b * 65536 + (n0 + srow) * 256 + kk + soff;
    *(short8*)&As[srow][soff]     = *(const short8*)(ga);
    *(short8*)&As[srow][soff + 8] = *(const short8*)(ga + 8);
    *(short8*)&Bs[srow][soff]     = *(const short8*)(gb);
    *(short8*)&Bs[srow][soff + 8] = *(const short8*)(gb + 8);
    __syncthreads();
#pragma unroll
    for (int ks = 0; ks < 2; ++ks) {
      short8 af[2], bf[2];
#pragma unroll
      for (int mi = 0; mi < 2; ++mi)
        af[mi] = *(const short8*)&As[wm * 32 + mi * 16 + lrow][ks * 32 + lk];
#pragma unroll
      for (int ni = 0; ni < 2; ++ni)
        bf[ni] = *(const short8*)&Bs[wn * 32 + ni * 16 + lrow][ks * 32 + lk];
#pragma unroll
      for (int mi = 0; mi < 2; ++mi)
#pragma unroll
        for (int ni = 0; ni < 2; ++ni)
          acc[mi][ni] = __builtin_amdgcn_mfma_f32_16x16x32_bf16(
              af[mi], bf[ni], acc[mi][ni], 0, 0, 0);
    }
    __syncthreads();
  }
#pragma unroll
  for (int mi = 0; mi < 2; ++mi)
#pragma unroll
    for (int ni = 0; ni < 2; ++ni) {
      int r0 = m0 + wm * 32 + mi * 16 + ((lane >> 4) << 2);
      int c = n0 + wn * 32 + ni * 16 + (lane & 15);
#pragma unroll
      for (int r = 0; r < 4; ++r)
        inp[((r0 + r) * 16 + b) * SIN + 256 + c] = f2bf(acc[mi][ni][r]);
    }
#pragma unroll
  for (int i = 0; i < 4; ++i) {
    int idx = i * 256 + tid;
    int so = idx >> 4, d4 = (idx & 15) << 2;
    float4 v4 = *(const float4*)(curb + b * bstride + (m0 + so) * sstride + n0 + d4);
    ushort4 o;
    o.x = f2bf(v4.x); o.y = f2bf(v4.y); o.z = f2bf(v4.z); o.w = f2bf(v4.w);
    *(ushort4*)(inp + ((m0 + so) * 16 + b) * SIN + n0 + d4) = o;
  }
}

// bf16 MFMA GEMM: U(dir) = inp(4096x512) @ W(dir)(512x512); 128x64 tile, BK=64
// U stored as bf16 (halves write + downstream read traffic)
__global__ __launch_bounds__(256) void k_mfma(const u16* __restrict__ inp,
    const u16* __restrict__ wt, u16* __restrict__ Uf, u16* __restrict__ Ub,
    int layer) {
  __shared__ u16 As[128][72];
  __shared__ u16 Bs[64][72];
  u16* U = blockIdx.z ? Ub : Uf;
  const u16* W = wt + (layer * 2 + blockIdx.z) * 262144;   // [n][k]
  int m0 = blockIdx.x * 128, n0 = blockIdx.y * 64;
  int tid = threadIdx.x;
  int wid = tid >> 6, lane = tid & 63;
  int wm = wid >> 1, wn = wid & 1;
  f32x4 acc[4][2];
#pragma unroll
  for (int i = 0; i < 4; ++i)
#pragma unroll
    for (int j = 0; j < 2; ++j) acc[i][j] = (f32x4){0.f, 0.f, 0.f, 0.f};
  int arow = tid >> 1, ahalf = tid & 1;
  int brow = tid >> 2, bq = tid & 3;
  int lrow = lane & 15, lk = (lane >> 4) << 3;
  for (int kk = 0; kk < 512; kk += 64) {
    const u16* ga = inp + (m0 + arow) * SIN + kk + ahalf * 32;
    const u16* gb = W + (n0 + brow) * 512 + kk + bq * 16;
#pragma unroll
    for (int j = 0; j < 4; ++j)
      *(short8*)&As[arow][ahalf * 32 + j * 8] = *(const short8*)(ga + j * 8);
    *(short8*)&Bs[brow][bq * 16]     = *(const short8*)(gb);
    *(short8*)&Bs[brow][bq * 16 + 8] = *(const short8*)(gb + 8);
    __syncthreads();
#pragma unroll
    for (int ks = 0; ks < 2; ++ks) {
      short8 af[4], bf[2];
#pragma unroll
      for (int mi = 0; mi < 4; ++mi)
        af[mi] = *(const short8*)&As[wm * 64 + mi * 16 + lrow][ks * 32 + lk];
#pragma unroll
      for (int ni = 0; ni < 2; ++ni)
        bf[ni] = *(const short8*)&Bs[wn * 32 + ni * 16 + lrow][ks * 32 + lk];
#pragma unroll
      for (int mi = 0; mi < 4; ++mi)
#pragma unroll
        for (int ni = 0; ni < 2; ++ni)
          acc[mi][ni] = __builtin_amdgcn_mfma_f32_16x16x32_bf16(
              af[mi], bf[ni], acc[mi][ni], 0, 0, 0);
    }
    __syncthreads();
  }
#pragma unroll
  for (int mi = 0; mi < 4; ++mi)
#pragma unroll
    for (int ni = 0; ni < 2; ++ni) {
      int r0 = m0 + wm * 64 + mi * 16 + ((lane >> 4) << 2);
      int c = n0 + wn * 32 + ni * 16 + (lane & 15);
#pragma unroll
      for (int r = 0; r < 4; ++r)
        U[(r0 + r) * F4H + c] = f2bf(acc[mi][ni][r]);
    }
}

// SRU segmented parallel scan on bf16 U; coalesced reads (chain = tid&15)
__global__ __launch_bounds__(256) void k_scan(const u16* __restrict__ Uf,
    const u16* __restrict__ Ub, const float* __restrict__ bfp,
    const float* __restrict__ bbp, float* __restrict__ obase,
    int o_sstride, int o_bstride, const int* __restrict__ status, int final) {
  __shared__ float so[16][257];
  __shared__ float sA[16][17], sB[16][17], sC[16][17];
  int tid = threadIdx.x;
  int c16 = tid & 15;                         // chain within block (h offset)
  int seg = tid >> 4;                         // 0..15, 16 steps each
  int chain = blockIdx.x * 16 + c16;          // dir*2048+b*128+h
  int dir = chain >> 11;
  int rem = chain & 2047;
  int b = rem >> 7, h = rem & 127;
  const u16* U = dir ? Ub : Uf;
  const float* bias = dir ? bbp : bfp;
  float bfv = bias[h], brv = bias[128 + h];
  const u16* up = U + b * 512 + h;
  int s0 = seg * 16;
  float fv[16], u0[16], rv[16], hw[16];
#pragma unroll
  for (int t = 0; t < 16; ++t) {
    const u16* q = up + (s0 + t) * 8192;
    u0[t] = bf2f(q[0]); fv[t] = bf2f(q[128]);
    rv[t] = bf2f(q[256]); hw[t] = bf2f(q[384]);
  }
  float A = 1.f, Bv = 0.f;
#pragma unroll
  for (int t = 0; t < 16; ++t) {
    float f = fast_sigmoid(fv[t] + bfv);
    fv[t] = f;
    Bv = f * Bv + (1.f - f) * u0[t];
    A = A * f;
  }
  sA[seg][c16] = A;
  sB[seg][c16] = Bv;
  __syncthreads();
  if (tid < 16) {                             // serial prefix over 16 segs
    float prevB = 0.f;
#pragma unroll
    for (int sgi = 0; sgi < 16; ++sgi) {
      sC[sgi][tid] = prevB;
      prevB = sA[sgi][tid] * prevB + sB[sgi][tid];
    }
  }
  __syncthreads();
  float c = sC[seg][c16];
#pragma unroll
  for (int t = 0; t < 16; ++t) {
    float f = fv[t];
    c = f * (c - u0[t]) + u0[t];
    float r = fast_sigmoid(rv[t] + brv);
    so[c16][s0 + t] = r * fast_tanh(c) + (1.f - r) * hw[t];
  }
  __syncthreads();
  bool ok = final ? (*status != 0) : true;
  int h_idx = tid & 15, s_idx = tid >> 4;
  int c2 = blockIdx.x * 16 + h_idx;
  int dir2 = c2 >> 11, rem2 = c2 & 2047;
  int b2 = rem2 >> 7, h2 = rem2 & 127;
  float* op2 = obase + b2 * o_bstride + dir2 * 128 + h2;
#pragma unroll
  for (int j = 0; j < 16; ++j) {
    int s = s_idx * 16 + j;
    float hv = so[h_idx][s];
    op2[s * o_sstride] = ok ? hv : 20.0f;
  }
}

__global__ __launch_bounds__(256) void k_fill(float* out, float v, int n) {
  int idx = blockIdx.x * 256 + threadIdx.x;
  if (idx < n) out[idx] = v;
}

extern "C" void kernel_launch(void* const* d_in, const int* in_sizes, int n_in,
                              void* d_out, int out_size, void* d_ws, size_t ws_size,
                              hipStream_t stream) {
  float* out = (float*)d_out;
  int fill_grid = (out_size + 255) / 256;

  const int exp_sizes[12] = {1048576, 4096, 16, 131072, 512, 131072, 512, 512,
                             524288, 512, 524288, 512};
  bool env_ok = (n_in == 12);
  if (env_ok)
    for (int i = 0; i < 12; ++i) env_ok = env_ok && (in_sizes[i] == exp_sizes[i]);
  if (!env_ok) {
    k_fill<<<fill_grid, 256, 0, stream>>>(out, 10.0f, out_size);
    return;
  }

  const float* x    = (const float*)d_in[0];
  const unsigned char* xmask = (const unsigned char*)d_in[1];
  const float* w1   = (const float*)d_in[3];
  const float* b1   = (const float*)d_in[4];
  const float* w2   = (const float*)d_in[5];
  const float* b2   = (const float*)d_in[6];
  const float* v    = (const float*)d_in[7];
  const float* sw_f = (const float*)d_in[8];
  const float* sb_f = (const float*)d_in[9];
  const float* sw_b = (const float*)d_in[10];
  const float* sb_b = (const float*)d_in[11];

  float* ws = (float*)d_ws;
  size_t off = 0;
  float* pb0    = ws + off; off += 1048576;
  float* xtT    = ws + off; off += 262144;
  float* yt     = ws + off; off += 262144;
  u16*   Uf     = (u16*)(ws + off); off += 1048576;   // 2M u16 (bf16 U)
  u16*   Ub     = (u16*)(ws + off); off += 1048576;
  u16*   scores = (u16*)(ws + off); off += 524288;    // 1M u16
  u16*   xT     = (u16*)(ws + off); off += 524288;    // 1M u16
  u16*   inp    = (u16*)(ws + off); off += 1048576;   // 2M u16
  u16*   wt     = (u16*)(ws + off); off += 524288;    // 1M u16
  int*   act    = (int*)(ws + off); off += 16;
  int*   status = (int*)(ws + off); off += 16;

  if (ws_size < off * sizeof(float)) {
    k_fill<<<fill_grid, 256, 0, stream>>>(out, 30.0f, out_size);
    return;
  }

  k_prep<<<dim3(8, 8, 20), 256, 0, stream>>>(sw_f, sw_b, wt, x, xT,
      (const int*)d_in[2], act, status);
  k_xt<<<dim3(16, 16), 256, 0, stream>>>(x, act, w1, b1, xtT);

  for (int layer = 0; layer < 2; ++layer) {
    const float* curb = layer ? pb0 : x;
    int sstride = layer ? 4096 : 256;
    int bstride = layer ? 256 : 65536;
    float* nxt      = layer ? out : pb0;
    int o_sstride   = layer ? 256 : 4096;
    int o_bstride   = layer ? 65536 : 256;
    k_yt<<<dim3(16, 16), 256, 0, stream>>>(curb, sstride, bstride, act, w2, b2, yt);
    k_score<<<512, 256, 0, stream>>>(xtT, yt, v, act, xmask, scores);
    k_poolm<<<dim3(4, 4, 16), 256, 0, stream>>>(scores, xT, curb, sstride,
                                                bstride, inp);
    k_mfma<<<dim3(32, 8, 2), 256, 0, stream>>>(inp, wt, Uf, Ub, layer);
    k_scan<<<256, 256, 0, stream>>>(Uf, Ub, sb_f + layer * 256, sb_b + layer * 256,
                                    nxt, o_sstride, o_bstride, status, layer);
  }
}

// Round 18
// 142.787 us; speedup vs baseline: 1.0702x; 1.0702x over previous
//
#include <hip/hip_runtime.h>
#include <hip/hip_bf16.h>

#define S_ 256
#define D_ 256
#define K_ 64
#define SIN 512
#define F4H 512

typedef unsigned short u16;
typedef __attribute__((ext_vector_type(8))) short short8;
typedef __attribute__((ext_vector_type(4))) float f32x4;

__device__ __forceinline__ float rcpf(float x) { return __builtin_amdgcn_rcpf(x); }
__device__ __forceinline__ float fast_sigmoid(float x) {
  return rcpf(1.0f + __expf(-x));
}
__device__ __forceinline__ float fast_tanh(float x) {
  return 1.0f - 2.0f * rcpf(__expf(2.0f * x) + 1.0f);
}
__device__ __forceinline__ u16 f2bf(float f) {   // RNE f32->bf16
  unsigned int u = __float_as_uint(f);
  return (u16)((u + 0x7fff + ((u >> 16) & 1)) >> 16);
}

// prologue: weights f32->bf16 transposed [layer*2+dir][n][k] (z<4);
// x f32->bf16 transposed xT[b][d][l] (z>=4); act decode in z==0 block.
__global__ __launch_bounds__(256) void k_prep(const float* __restrict__ sw_f,
    const float* __restrict__ sw_b, u16* __restrict__ wt,
    const float* __restrict__ x, u16* __restrict__ xT,
    const int* __restrict__ araw, int* __restrict__ act_out,
    int* __restrict__ status) {
  if (blockIdx.x == 0 && blockIdx.y == 0 && blockIdx.z == 0 && threadIdx.x == 0) {
    bool oddzero = true;
    for (int i = 1; i < 16; i += 2) oddzero = oddzero && (araw[i] == 0);
    bool ok = true;
    for (int b = 0; b < 16; ++b) {
      int v = oddzero ? araw[2 * b] : araw[b];
      act_out[b] = (v < 0) ? 0 : (v > 7 ? 7 : v);
      ok = ok && (v >= 0 && v < 8);
    }
    *status = ok ? 1 : 0;
  }
  __shared__ u16 tile[64][66];
  int tj = threadIdx.x & 63, ti = threadIdx.x >> 6;
  int z = blockIdx.z;
  if (z < 4) {                         // SRU weight transpose
    int layer = z >> 1;
    const float* src = (z & 1) ? sw_b : sw_f;
    int k0 = blockIdx.x * 64, n0 = blockIdx.y * 64;
#pragma unroll
    for (int i = ti; i < 64; i += 4)
      tile[i][tj] = f2bf(src[layer * 262144 + (k0 + i) * 512 + n0 + tj]);
    __syncthreads();
#pragma unroll
    for (int j = ti; j < 64; j += 4)
      wt[z * 262144 + (n0 + j) * 512 + k0 + tj] = tile[tj][j];
  } else {                             // x transpose -> xT[b][d][l] bf16
    if (blockIdx.x >= 4 || blockIdx.y >= 4) return;
    int b = z - 4;
    int l0 = blockIdx.x * 64, d0 = blockIdx.y * 64;
#pragma unroll
    for (int i = ti; i < 64; i += 4)
      tile[i][tj] = f2bf(x[b * 65536 + (l0 + i) * 256 + d0 + tj]);
    __syncthreads();
#pragma unroll
    for (int j = ti; j < 64; j += 4)
      xT[b * 65536 + (d0 + j) * 256 + l0 + tj] = tile[tj][j];
  }
}

// 16-row tile GEMM -> TRANSPOSED store: xtT[(b*64+n)*256+l]
__global__ __launch_bounds__(256) void k_xt(const float* __restrict__ x,
    const int* __restrict__ act, const float* __restrict__ w1,
    const float* __restrict__ b1, float* __restrict__ xtT) {
  __shared__ float As[16][17], Bs[16][68];
  int b = blockIdx.y;
  int a = act[b];
  int l0 = blockIdx.x * 16;
  const float* A = x + b * (S_ * D_);
  const float* W = w1 + a * (D_ * K_);
  int tid = threadIdx.x;
  int ty = tid >> 4, tx = tid & 15;
  float acc[4] = {};
  for (int kk = 0; kk < D_; kk += 16) {
    As[ty][tx] = A[(l0 + ty) * D_ + kk + tx];
    *(float4*)&Bs[ty][tx << 2] = *(const float4*)(W + (kk + ty) * K_ + (tx << 2));
    __syncthreads();
#pragma unroll
    for (int k = 0; k < 16; ++k) {
      float av = As[ty][k];
      acc[0] += av * Bs[k][(tx << 2) + 0];
      acc[1] += av * Bs[k][(tx << 2) + 1];
      acc[2] += av * Bs[k][(tx << 2) + 2];
      acc[3] += av * Bs[k][(tx << 2) + 3];
    }
    __syncthreads();
  }
#pragma unroll
  for (int j = 0; j < 4; ++j) {
    int n = (tx << 2) + j;
    xtT[(b << 14) + n * 256 + l0 + ty] = acc[j] + b1[a * K_ + n];
  }
}

// 16-row tile: yt[((s0+r)*16+b)*64+n]
__global__ __launch_bounds__(256) void k_yt(const float* __restrict__ curb,
    int sstride, int bstride, const int* __restrict__ act,
    const float* __restrict__ w2, const float* __restrict__ b2,
    float* __restrict__ yt) {
  __shared__ float As[16][17], Bs[16][68];
  int b = blockIdx.y;
  int a = act[b];
  int s0 = blockIdx.x * 16;
  const float* A = curb + b * bstride;
  const float* W = w2 + a * (D_ * K_);
  int tid = threadIdx.x;
  int ty = tid >> 4, tx = tid & 15;
  float acc[4] = {};
  for (int kk = 0; kk < D_; kk += 16) {
    As[ty][tx] = A[(s0 + ty) * sstride + kk + tx];
    *(float4*)&Bs[ty][tx << 2] = *(const float4*)(W + (kk + ty) * K_ + (tx << 2));
    __syncthreads();
#pragma unroll
    for (int k = 0; k < 16; ++k) {
      float av = As[ty][k];
      acc[0] += av * Bs[k][(tx << 2) + 0];
      acc[1] += av * Bs[k][(tx << 2) + 1];
      acc[2] += av * Bs[k][(tx << 2) + 2];
      acc[3] += av * Bs[k][(tx << 2) + 3];
    }
    __syncthreads();
  }
  float4 o;
  o.x = acc[0] + b2[a * K_ + (tx << 2) + 0];
  o.y = acc[1] + b2[a * K_ + (tx << 2) + 1];
  o.z = acc[2] + b2[a * K_ + (tx << 2) + 2];
  o.w = acc[3] + b2[a * K_ + (tx << 2) + 3];
  *(float4*)(yt + ((s0 + ty) * 16 + b) * K_ + (tx << 2)) = o;
}

// scores+softmax, 4 s-rows/block, 1024 blocks; bf16 probs out
__global__ __launch_bounds__(256) void k_score(const float* __restrict__ xtT,
    const float* __restrict__ yt, const float* __restrict__ v,
    const int* __restrict__ act, const unsigned char* __restrict__ xmask,
    u16* __restrict__ scores) {
  __shared__ float yts[4][K_], vas[K_];
  __shared__ float redm[4][4], reds[4][4];
  int tid = threadIdx.x;               // = l
  int bid = blockIdx.x;                // s4*16 + b
  int b = bid & 15, s4 = bid >> 4;
  int a = act[b];
  if (tid < 64) vas[tid] = v[a * K_ + tid];
  {
    int row = tid >> 6, k = tid & 63;
    yts[row][k] = yt[((s4 * 4 + row) * 16 + b) * K_ + k];
  }
  __syncthreads();
  float acc0 = 0.f, acc1 = 0.f, acc2 = 0.f, acc3 = 0.f;
  {
    const float* xb = xtT + (b << 14) + tid;
#pragma unroll
    for (int k = 0; k < 64; ++k) {
      float xv = xb[k * 256];
      float vv = vas[k];
      acc0 += vv * fast_tanh(xv + yts[0][k]);
      acc1 += vv * fast_tanh(xv + yts[1][k]);
      acc2 += vv * fast_tanh(xv + yts[2][k]);
      acc3 += vv * fast_tanh(xv + yts[3][k]);
    }
    if (xmask[b * S_ + tid]) { acc0 = acc1 = acc2 = acc3 = -1e30f; }
  }
  int wid = tid >> 6;
  float m0 = acc0, m1 = acc1, m2 = acc2, m3 = acc3;
#pragma unroll
  for (int d = 32; d; d >>= 1) {
    m0 = fmaxf(m0, __shfl_xor(m0, d));
    m1 = fmaxf(m1, __shfl_xor(m1, d));
    m2 = fmaxf(m2, __shfl_xor(m2, d));
    m3 = fmaxf(m3, __shfl_xor(m3, d));
  }
  if ((tid & 63) == 0) {
    redm[0][wid] = m0; redm[1][wid] = m1; redm[2][wid] = m2; redm[3][wid] = m3;
  }
  __syncthreads();
  m0 = fmaxf(fmaxf(redm[0][0], redm[0][1]), fmaxf(redm[0][2], redm[0][3]));
  m1 = fmaxf(fmaxf(redm[1][0], redm[1][1]), fmaxf(redm[1][2], redm[1][3]));
  m2 = fmaxf(fmaxf(redm[2][0], redm[2][1]), fmaxf(redm[2][2], redm[2][3]));
  m3 = fmaxf(fmaxf(redm[3][0], redm[3][1]), fmaxf(redm[3][2], redm[3][3]));
  float p0 = __expf(acc0 - m0), p1 = __expf(acc1 - m1);
  float p2 = __expf(acc2 - m2), p3 = __expf(acc3 - m3);
  float s0 = p0, s1 = p1, s2 = p2, s3 = p3;
#pragma unroll
  for (int d = 32; d; d >>= 1) {
    s0 += __shfl_xor(s0, d);
    s1 += __shfl_xor(s1, d);
    s2 += __shfl_xor(s2, d);
    s3 += __shfl_xor(s3, d);
  }
  if ((tid & 63) == 0) {
    reds[0][wid] = s0; reds[1][wid] = s1; reds[2][wid] = s2; reds[3][wid] = s3;
  }
  __syncthreads();
  s0 = reds[0][0] + reds[0][1] + reds[0][2] + reds[0][3];
  s1 = reds[1][0] + reds[1][1] + reds[1][2] + reds[1][3];
  s2 = reds[2][0] + reds[2][1] + reds[2][2] + reds[2][3];
  s3 = reds[3][0] + reds[3][1] + reds[3][2] + reds[3][3];
  u16* dst = scores + ((s4 * 4) * 16 + b) * 256 + tid;
  dst[0]        = f2bf(p0 * rcpf(s0));
  dst[16 * 256] = f2bf(p1 * rcpf(s1));
  dst[32 * 256] = f2bf(p2 * rcpf(s2));
  dst[48 * 256] = f2bf(p3 * rcpf(s3));
}

// bf16 MFMA pool: pools = att(bf16) @ xT(bf16)^T per batch; 64x64 tile, BK=64
__global__ __launch_bounds__(256) void k_poolm(const u16* __restrict__ scores,
    const u16* __restrict__ xT, const float* __restrict__ curb,
    int sstride, int bstride, u16* __restrict__ inp) {
  __shared__ u16 As[64][72];
  __shared__ u16 Bs[64][72];
  int b = blockIdx.z;
  int m0 = blockIdx.x * 64, n0 = blockIdx.y * 64;   // s, d
  int tid = threadIdx.x;
  int wid = tid >> 6, lane = tid & 63;
  int wm = wid >> 1, wn = wid & 1;
  f32x4 acc[2][2];
#pragma unroll
  for (int i = 0; i < 2; ++i)
#pragma unroll
    for (int j = 0; j < 2; ++j) acc[i][j] = (f32x4){0.f, 0.f, 0.f, 0.f};
  int srow = tid >> 2, soff = (tid & 3) * 16;
  int lrow = lane & 15, lk = (lane >> 4) << 3;
  for (int kk = 0; kk < 256; kk += 64) {
    const u16* ga = scores + ((m0 + srow) * 16 + b) * 256 + kk + soff;
    const u16* gb = xT + b * 65536 + (n0 + srow) * 256 + kk + soff;
    *(short8*)&As[srow][soff]     = *(const short8*)(ga);
    *(short8*)&As[srow][soff + 8] = *(const short8*)(ga + 8);
    *(short8*)&Bs[srow][soff]     = *(const short8*)(gb);
    *(short8*)&Bs[srow][soff + 8] = *(const short8*)(gb + 8);
    __syncthreads();
#pragma unroll
    for (int ks = 0; ks < 2; ++ks) {
      short8 af[2], bf[2];
#pragma unroll
      for (int mi = 0; mi < 2; ++mi)
        af[mi] = *(const short8*)&As[wm * 32 + mi * 16 + lrow][ks * 32 + lk];
#pragma unroll
      for (int ni = 0; ni < 2; ++ni)
        bf[ni] = *(const short8*)&Bs[wn * 32 + ni * 16 + lrow][ks * 32 + lk];
#pragma unroll
      for (int mi = 0; mi < 2; ++mi)
#pragma unroll
        for (int ni = 0; ni < 2; ++ni)
          acc[mi][ni] = __builtin_amdgcn_mfma_f32_16x16x32_bf16(
              af[mi], bf[ni], acc[mi][ni], 0, 0, 0);
    }
    __syncthreads();
  }
#pragma unroll
  for (int mi = 0; mi < 2; ++mi)
#pragma unroll
    for (int ni = 0; ni < 2; ++ni) {
      int r0 = m0 + wm * 32 + mi * 16 + ((lane >> 4) << 2);
      int c = n0 + wn * 32 + ni * 16 + (lane & 15);
#pragma unroll
      for (int r = 0; r < 4; ++r)
        inp[((r0 + r) * 16 + b) * SIN + 256 + c] = f2bf(acc[mi][ni][r]);
    }
#pragma unroll
  for (int i = 0; i < 4; ++i) {
    int idx = i * 256 + tid;
    int so = idx >> 4, d4 = (idx & 15) << 2;
    float4 v4 = *(const float4*)(curb + b * bstride + (m0 + so) * sstride + n0 + d4);
    ushort4 o;
    o.x = f2bf(v4.x); o.y = f2bf(v4.y); o.z = f2bf(v4.z); o.w = f2bf(v4.w);
    *(ushort4*)(inp + ((m0 + so) * 16 + b) * SIN + n0 + d4) = o;
  }
}

// bf16 MFMA GEMM: U(dir) = inp(4096x512) @ W(dir)(512x512); 128x64 tile, BK=64
// grid (32,8,2) = 512 blocks -> 2 blocks/CU
__global__ __launch_bounds__(256) void k_mfma(const u16* __restrict__ inp,
    const u16* __restrict__ wt, float* __restrict__ Uf, float* __restrict__ Ub,
    int layer) {
  __shared__ u16 As[128][72];
  __shared__ u16 Bs[64][72];
  float* U = blockIdx.z ? Ub : Uf;
  const u16* W = wt + (layer * 2 + blockIdx.z) * 262144;   // [n][k]
  int m0 = blockIdx.x * 128, n0 = blockIdx.y * 64;
  int tid = threadIdx.x;
  int wid = tid >> 6, lane = tid & 63;
  int wm = wid >> 1, wn = wid & 1;
  f32x4 acc[4][2];
#pragma unroll
  for (int i = 0; i < 4; ++i)
#pragma unroll
    for (int j = 0; j < 2; ++j) acc[i][j] = (f32x4){0.f, 0.f, 0.f, 0.f};
  int arow = tid >> 1, ahalf = tid & 1;
  int brow = tid >> 2, bq = tid & 3;
  int lrow = lane & 15, lk = (lane >> 4) << 3;
  for (int kk = 0; kk < 512; kk += 64) {
    const u16* ga = inp + (m0 + arow) * SIN + kk + ahalf * 32;
    const u16* gb = W + (n0 + brow) * 512 + kk + bq * 16;
#pragma unroll
    for (int j = 0; j < 4; ++j)
      *(short8*)&As[arow][ahalf * 32 + j * 8] = *(const short8*)(ga + j * 8);
    *(short8*)&Bs[brow][bq * 16]     = *(const short8*)(gb);
    *(short8*)&Bs[brow][bq * 16 + 8] = *(const short8*)(gb + 8);
    __syncthreads();
#pragma unroll
    for (int ks = 0; ks < 2; ++ks) {
      short8 af[4], bf[2];
#pragma unroll
      for (int mi = 0; mi < 4; ++mi)
        af[mi] = *(const short8*)&As[wm * 64 + mi * 16 + lrow][ks * 32 + lk];
#pragma unroll
      for (int ni = 0; ni < 2; ++ni)
        bf[ni] = *(const short8*)&Bs[wn * 32 + ni * 16 + lrow][ks * 32 + lk];
#pragma unroll
      for (int mi = 0; mi < 4; ++mi)
#pragma unroll
        for (int ni = 0; ni < 2; ++ni)
          acc[mi][ni] = __builtin_amdgcn_mfma_f32_16x16x32_bf16(
              af[mi], bf[ni], acc[mi][ni], 0, 0, 0);
    }
    __syncthreads();
  }
#pragma unroll
  for (int mi = 0; mi < 4; ++mi)
#pragma unroll
    for (int ni = 0; ni < 2; ++ni) {
      int r0 = m0 + wm * 64 + mi * 16 + ((lane >> 4) << 2);
      int c = n0 + wn * 32 + ni * 16 + (lane & 15);
#pragma unroll
      for (int r = 0; r < 4; ++r)
        U[(r0 + r) * F4H + c] = acc[mi][ni][r];
    }
}

// SRU segmented parallel scan, COALESCED U reads:
// chain = tid&15 (consecutive h -> contiguous 64B), seg = tid>>4.
// Cross-segment prefix via small LDS serial scan (segs span waves).
__global__ __launch_bounds__(256) void k_scan(const float* __restrict__ Uf,
    const float* __restrict__ Ub, const float* __restrict__ bfp,
    const float* __restrict__ bbp, float* __restrict__ obase,
    int o_sstride, int o_bstride, const int* __restrict__ status, int final) {
  __shared__ float so[16][257];
  __shared__ float sA[16][17], sB[16][17], sC[16][17];
  int tid = threadIdx.x;
  int c16 = tid & 15;                         // chain within block (h offset)
  int seg = tid >> 4;                         // 0..15, 16 steps each
  int chain = blockIdx.x * 16 + c16;          // dir*2048+b*128+h
  int dir = chain >> 11;
  int rem = chain & 2047;
  int b = rem >> 7, h = rem & 127;
  const float* U = dir ? Ub : Uf;
  const float* bias = dir ? bbp : bfp;
  float bfv = bias[h], brv = bias[128 + h];
  const float* up = U + b * 512 + h;
  int s0 = seg * 16;
  float fv[16], u0[16], rv[16], hw[16];
#pragma unroll
  for (int t = 0; t < 16; ++t) {
    const float* q = up + (s0 + t) * 8192;    // lanes: 16 contiguous h x 4 segs
    u0[t] = q[0]; fv[t] = q[128]; rv[t] = q[256]; hw[t] = q[384];
  }
  float A = 1.f, Bv = 0.f;
#pragma unroll
  for (int t = 0; t < 16; ++t) {
    float f = fast_sigmoid(fv[t] + bfv);
    fv[t] = f;
    Bv = f * Bv + (1.f - f) * u0[t];
    A = A * f;
  }
  sA[seg][c16] = A;
  sB[seg][c16] = Bv;
  __syncthreads();
  if (tid < 16) {                             // serial prefix over 16 segs, chain=tid
    float prevB = 0.f;                        // c0 = 0 -> only B-from-zero needed
#pragma unroll
    for (int sgi = 0; sgi < 16; ++sgi) {
      sC[sgi][tid] = prevB;                   // exclusive prefix (c entering seg)
      prevB = sA[sgi][tid] * prevB + sB[sgi][tid];
    }
  }
  __syncthreads();
  float c = sC[seg][c16];
#pragma unroll
  for (int t = 0; t < 16; ++t) {
    float f = fv[t];
    c = f * (c - u0[t]) + u0[t];
    float r = fast_sigmoid(rv[t] + brv);
    so[c16][s0 + t] = r * fast_tanh(c) + (1.f - r) * hw[t];
  }
  __syncthreads();
  // coalesced write-out
  bool ok = final ? (*status != 0) : true;
  int h_idx = tid & 15, s_idx = tid >> 4;
  int c2 = blockIdx.x * 16 + h_idx;
  int dir2 = c2 >> 11, rem2 = c2 & 2047;
  int b2 = rem2 >> 7, h2 = rem2 & 127;
  float* op2 = obase + b2 * o_bstride + dir2 * 128 + h2;
#pragma unroll
  for (int j = 0; j < 16; ++j) {
    int s = s_idx * 16 + j;
    float hv = so[h_idx][s];
    op2[s * o_sstride] = ok ? hv : 20.0f;
  }
}

__global__ __launch_bounds__(256) void k_fill(float* out, float v, int n) {
  int idx = blockIdx.x * 256 + threadIdx.x;
  if (idx < n) out[idx] = v;
}

extern "C" void kernel_launch(void* const* d_in, const int* in_sizes, int n_in,
                              void* d_out, int out_size, void* d_ws, size_t ws_size,
                              hipStream_t stream) {
  float* out = (float*)d_out;
  int fill_grid = (out_size + 255) / 256;

  const int exp_sizes[12] = {1048576, 4096, 16, 131072, 512, 131072, 512, 512,
                             524288, 512, 524288, 512};
  bool env_ok = (n_in == 12);
  if (env_ok)
    for (int i = 0; i < 12; ++i) env_ok = env_ok && (in_sizes[i] == exp_sizes[i]);
  if (!env_ok) {
    k_fill<<<fill_grid, 256, 0, stream>>>(out, 10.0f, out_size);
    return;
  }

  const float* x    = (const float*)d_in[0];
  const unsigned char* xmask = (const unsigned char*)d_in[1];
  const float* w1   = (const float*)d_in[3];
  const float* b1   = (const float*)d_in[4];
  const float* w2   = (const float*)d_in[5];
  const float* b2   = (const float*)d_in[6];
  const float* v    = (const float*)d_in[7];
  const float* sw_f = (const float*)d_in[8];
  const float* sb_f = (const float*)d_in[9];
  const float* sw_b = (const float*)d_in[10];
  const float* sb_b = (const float*)d_in[11];

  float* ws = (float*)d_ws;
  size_t off = 0;
  float* pb0    = ws + off; off += 1048576;
  float* xtT    = ws + off; off += 262144;
  float* yt     = ws + off; off += 262144;
  float* Uf     = ws + off; off += 2097152;
  float* Ub     = ws + off; off += 2097152;
  u16*   scores = (u16*)(ws + off); off += 524288;    // 1M u16
  u16*   xT     = (u16*)(ws + off); off += 524288;    // 1M u16
  u16*   inp    = (u16*)(ws + off); off += 1048576;   // 2M u16
  u16*   wt     = (u16*)(ws + off); off += 524288;    // 1M u16
  int*   act    = (int*)(ws + off); off += 16;
  int*   status = (int*)(ws + off); off += 16;

  if (ws_size < off * sizeof(float)) {
    k_fill<<<fill_grid, 256, 0, stream>>>(out, 30.0f, out_size);
    return;
  }

  k_prep<<<dim3(8, 8, 20), 256, 0, stream>>>(sw_f, sw_b, wt, x, xT,
      (const int*)d_in[2], act, status);
  k_xt<<<dim3(16, 16), 256, 0, stream>>>(x, act, w1, b1, xtT);

  for (int layer = 0; layer < 2; ++layer) {
    const float* curb = layer ? pb0 : x;
    int sstride = layer ? 4096 : 256;
    int bstride = layer ? 256 : 65536;
    float* nxt      = layer ? out : pb0;
    int o_sstride   = layer ? 256 : 4096;
    int o_bstride   = layer ? 65536 : 256;
    k_yt<<<dim3(16, 16), 256, 0, stream>>>(curb, sstride, bstride, act, w2, b2, yt);
    k_score<<<1024, 256, 0, stream>>>(xtT, yt, v, act, xmask, scores);
    k_poolm<<<dim3(4, 4, 16), 256, 0, stream>>>(scores, xT, curb, sstride,
                                                bstride, inp);
    k_mfma<<<dim3(32, 8, 2), 256, 0, stream>>>(inp, wt, Uf, Ub, layer);
    k_scan<<<256, 256, 0, stream>>>(Uf, Ub, sb_f + layer * 256, sb_b + layer * 256,
                                    nxt, o_sstride, o_bstride, status, layer);
  }
}